// Round 10
// baseline (496.381 us; speedup 1.0000x reference)
//
#include <hip/hip_runtime.h>

#define LL 32
#define HH 64

template <int CTRL>
__device__ __forceinline__ float dpp_add_step(float x) {
  int y = __builtin_amdgcn_update_dpp(0, __builtin_bit_cast(int, x), CTRL, 0xf, 0xf, true);
  return x + __builtin_bit_cast(float, y);
}

// 64-lane sum -> uniform value (via readlane 63).
__device__ __forceinline__ float wave_sum64(float x) {
  x = dpp_add_step<0x111>(x);  // row_shr:1
  x = dpp_add_step<0x112>(x);  // row_shr:2
  x = dpp_add_step<0x114>(x);  // row_shr:4
  x = dpp_add_step<0x118>(x);  // row_shr:8
  x = dpp_add_step<0x142>(x);  // row_bcast15
  x = dpp_add_step<0x143>(x);  // row_bcast31
  return __builtin_bit_cast(float, __builtin_amdgcn_readlane(__builtin_bit_cast(int, x), 63));
}

#define DECL_W(n) float w_##n = Wc[n * HH + lane];
#define MV4(g, i0, i1, i2, i3)        \
  {                                   \
    const float4 hb = hv4[g];         \
    a0 = fmaf(hb.x, w_##i0, a0);      \
    a1 = fmaf(hb.y, w_##i1, a1);      \
    a2 = fmaf(hb.z, w_##i2, a2);      \
    a3 = fmaf(hb.w, w_##i3, a3);      \
  }

// One-time pin after preload: all weights become asm-defined VGPR values
// (cannot be rematerialized as loads). NOT inside the loop — R5/R6 showed
// in-loop placement is neutral at best and it fences the scheduler.
#define PIN_ALL_W                                                              \
  asm volatile(""                                                              \
               : "+v"(w_0), "+v"(w_1), "+v"(w_2), "+v"(w_3), "+v"(w_4),       \
                 "+v"(w_5), "+v"(w_6), "+v"(w_7), "+v"(w_8), "+v"(w_9),       \
                 "+v"(w_10), "+v"(w_11), "+v"(w_12), "+v"(w_13), "+v"(w_14),  \
                 "+v"(w_15), "+v"(w_16), "+v"(w_17), "+v"(w_18), "+v"(w_19),  \
                 "+v"(w_20), "+v"(w_21), "+v"(w_22), "+v"(w_23), "+v"(w_24),  \
                 "+v"(w_25), "+v"(w_26), "+v"(w_27), "+v"(w_28), "+v"(w_29),  \
                 "+v"(w_30), "+v"(w_31), "+v"(w_32), "+v"(w_33), "+v"(w_34),  \
                 "+v"(w_35), "+v"(w_36), "+v"(w_37), "+v"(w_38), "+v"(w_39),  \
                 "+v"(w_40), "+v"(w_41), "+v"(w_42), "+v"(w_43), "+v"(w_44),  \
                 "+v"(w_45), "+v"(w_46), "+v"(w_47), "+v"(w_48), "+v"(w_49),  \
                 "+v"(w_50), "+v"(w_51), "+v"(w_52), "+v"(w_53), "+v"(w_54),  \
                 "+v"(w_55), "+v"(w_56), "+v"(w_57), "+v"(w_58), "+v"(w_59),  \
                 "+v"(w_60), "+v"(w_61), "+v"(w_62), "+v"(w_63), "+v"(win0),  \
                 "+v"(win1), "+v"(bcj), "+v"(dwout));

// One wave per sample, 1024 blocks = 1 wave/SIMD on all 1024 SIMDs (R7: with
// exactly B=1024 waves, concentrating waves trades SIMD count 1:1 — net loss).
__global__ __launch_bounds__(64, 1) void rnn2d_kernel(
    const int* __restrict__ x, const float* __restrict__ Win,
    const float* __restrict__ Wc, const float* __restrict__ bc,
    const float* __restrict__ Wout, const float* __restrict__ bout,
    float* __restrict__ out) {
  const int lane = threadIdx.x;
  const int b = blockIdx.x;
  __shared__ float vrow[LL * HH];  // vertical carry [column][hidden]
  __shared__ float hvbuf[2 * HH];  // double-buffered hv (compile-time parity)

  DECL_W(0)  DECL_W(1)  DECL_W(2)  DECL_W(3)  DECL_W(4)  DECL_W(5)  DECL_W(6)  DECL_W(7)
  DECL_W(8)  DECL_W(9)  DECL_W(10) DECL_W(11) DECL_W(12) DECL_W(13) DECL_W(14) DECL_W(15)
  DECL_W(16) DECL_W(17) DECL_W(18) DECL_W(19) DECL_W(20) DECL_W(21) DECL_W(22) DECL_W(23)
  DECL_W(24) DECL_W(25) DECL_W(26) DECL_W(27) DECL_W(28) DECL_W(29) DECL_W(30) DECL_W(31)
  DECL_W(32) DECL_W(33) DECL_W(34) DECL_W(35) DECL_W(36) DECL_W(37) DECL_W(38) DECL_W(39)
  DECL_W(40) DECL_W(41) DECL_W(42) DECL_W(43) DECL_W(44) DECL_W(45) DECL_W(46) DECL_W(47)
  DECL_W(48) DECL_W(49) DECL_W(50) DECL_W(51) DECL_W(52) DECL_W(53) DECL_W(54) DECL_W(55)
  DECL_W(56) DECL_W(57) DECL_W(58) DECL_W(59) DECL_W(60) DECL_W(61) DECL_W(62) DECL_W(63)

  float win0 = Win[lane];
  float win1 = Win[HH + lane];
  float bcj = bc[lane];
  float dwout = Wout[lane * 2 + 1] - Wout[lane * 2 + 0];
  const float dbout = bout[1] - bout[0];
  PIN_ALL_W

#pragma unroll
  for (int c0 = 0; c0 < LL; ++c0) vrow[c0 * HH + lane] = 0.f;
  hvbuf[lane] = 0.f;  // buffer 0: hv for (r=0, k=0)

  const int* xb = x + b * (LL * LL);
  unsigned prevmask = 0u;
  int spv = (lane < LL) ? xb[lane] : 0;
  float total_vec = 0.f;
  float dzbuf = 0.f;  // lane k holds step-k signed logit gap (rebuilt each row)

  // One scan step. hasH/hasNext are call-site constants (fold after inline);
  // hasV is wave-uniform runtime. Static rdoff/wroff -> immediate-offset DS ops.
  auto scan_step = [&](int k, int c, int cn, int rdoff, int wroff, int hasH,
                       int hasV, int hasNext, int d, unsigned curmask) {
    // Early: next vertical carry (lane-strided, conflict-free; consumed late).
    const float vjn = hasNext ? vrow[cn * HH + lane] : 0.f;

    const float4* hv4 = (const float4*)(hvbuf + rdoff);
    float a0 = 0.f, a1 = 0.f, a2 = 0.f, a3 = 0.f;
    MV4(0, 0, 1, 2, 3)      MV4(1, 4, 5, 6, 7)      MV4(2, 8, 9, 10, 11)
    MV4(3, 12, 13, 14, 15)  MV4(4, 16, 17, 18, 19)  MV4(5, 20, 21, 22, 23)
    MV4(6, 24, 25, 26, 27)  MV4(7, 28, 29, 30, 31)  MV4(8, 32, 33, 34, 35)
    MV4(9, 36, 37, 38, 39)  MV4(10, 40, 41, 42, 43) MV4(11, 44, 45, 46, 47)
    MV4(12, 48, 49, 50, 51) MV4(13, 52, 53, 54, 55) MV4(14, 56, 57, 58, 59)
    MV4(15, 60, 61, 62, 63)

    float winc = bcj;
    if (hasH) {
      const unsigned sh = (curmask >> ((c - d) & 31)) & 1u;
      winc += sh ? win1 : win0;
    }
    winc += hasV ? (((prevmask >> c) & 1u) ? win1 : win0) : 0.f;

    const float pre = ((a0 + a1) + (a2 + a3)) + winc;
    const float hnew = pre > 0.f ? pre : (__expf(pre) - 1.f);  // elu

    vrow[c * HH + lane] = hnew;
    // Next step's hv stored ASAP (k=31: next row re-enters same column with
    // zero horizontal carry -> hv = hnew + 0; uniform rule via hasNext).
    hvbuf[wroff + lane] = hnew + vjn;

    // Deferred logp: uniform signed gap (sign flipped by spin via xor) stashed
    // into lane k (v_cmp+v_cndmask; writelane builtin not exposed on this ROCm).
    const float dzf = wave_sum64(hnew * dwout) + dbout;
    const unsigned spin = (curmask >> c) & 1u;
    const float tv = __builtin_bit_cast(float, __builtin_bit_cast(unsigned, dzf) ^ (spin << 31));
    dzbuf = (lane == k) ? tv : dzbuf;
  };

#pragma unroll 1
  for (int r = 0; r < LL; ++r) {
    const unsigned curmask = (unsigned)(__ballot(lane < LL && spv) & 0xffffffffull);
    if (r < LL - 1) spv = (lane < LL) ? xb[(r + 1) * LL + lane] : 0;

    const int odd = r & 1;
    const int d = odd ? -1 : 1;
    const int rnz = r > 0;
    int c = odd ? (LL - 1) : 0;

    // k=0: read buf0, write buf1; no horizontal neighbor.
    scan_step(0, c, c + d, 0, HH, 0, rnz, 1, d, curmask);
    c += d;
    // k=1..30: 2-step body with static parity (odd k: buf1->buf0, even: 0->1).
#pragma unroll 1
    for (int k = 1; k <= LL - 3; k += 2) {
      scan_step(k, c, c + d, HH, 0, 1, rnz, 1, d, curmask);
      c += d;
      scan_step(k + 1, c, c + d, 0, HH, 1, rnz, 1, d, curmask);
      c += d;
    }
    // k=31: read buf1, write buf0 (feeds next row's k=0); no next column.
    scan_step(LL - 1, c, c, HH, 0, 1, rnz, 0, d, curmask);

    prevmask = curmask;

    // Row epilogue: softplus for all 32 sites at once (lanes 0..31 hold t_k).
    const float tt = dzbuf;
    float lpv = -(fmaxf(tt, 0.f) + __logf(1.f + __expf(-fabsf(tt))));
    lpv = (lpv == lpv) ? lpv : -35.0f;  // nan_to_num(nan=-35)
    total_vec += (lane < LL) ? lpv : 0.f;
  }

  const float grand = wave_sum64(total_vec);
  if (lane == 0) out[b] = 0.5f * grand;  // LOGP_FACTOR * sum
}

extern "C" void kernel_launch(void* const* d_in, const int* in_sizes, int n_in,
                              void* d_out, int out_size, void* d_ws, size_t ws_size,
                              hipStream_t stream) {
  const int* x = (const int*)d_in[0];
  const float* Win = (const float*)d_in[1];
  const float* Wc = (const float*)d_in[2];
  const float* bc = (const float*)d_in[3];
  const float* Wout = (const float*)d_in[4];
  const float* bout = (const float*)d_in[5];
  float* out = (float*)d_out;
  rnn2d_kernel<<<dim3(out_size), dim3(64), 0, stream>>>(x, Win, Wc, bc, Wout, bout, out);
}

// Round 11
// 391.909 us; speedup vs baseline: 1.2666x; 1.2666x over previous
//
#include <hip/hip_runtime.h>

#define LL 32
#define HH 64

typedef __attribute__((ext_vector_type(4))) float f32x4;

template <int CTRL>
__device__ __forceinline__ float dpp_add_step(float x) {
  int y = __builtin_amdgcn_update_dpp(0, __builtin_bit_cast(int, x), CTRL, 0xf, 0xf, true);
  return x + __builtin_bit_cast(float, y);
}

// 64-lane sum -> uniform value (via readlane 63).
__device__ __forceinline__ float wave_sum64(float x) {
  x = dpp_add_step<0x111>(x);  // row_shr:1
  x = dpp_add_step<0x112>(x);  // row_shr:2
  x = dpp_add_step<0x114>(x);  // row_shr:4
  x = dpp_add_step<0x118>(x);  // row_shr:8
  x = dpp_add_step<0x142>(x);  // row_bcast15
  x = dpp_add_step<0x143>(x);  // row_bcast31
  return __builtin_bit_cast(float, __builtin_amdgcn_readlane(__builtin_bit_cast(int, x), 63));
}

#define DECL_W(n) float w_##n = Wc[n * HH + lane];

// Stage one wave-uniform float4 broadcast group into a named register quad.
#define LOADG(n) f32x4 g##n = hv4[n];

// All 16 staged groups pinned live simultaneously: forces 64 landing VGPRs so
// the 16 ds_read_b128 pipeline at throughput (~12 cyc each) instead of
// serializing latency-bound. R8's VGPR_Count=72 (= 68 pinned weights + 4
// accumulators, zero landing regs) is why its reads serialized (~926 cyc/step).
#define PIN_ALL_G                                                             \
  asm volatile(""                                                             \
               : "+v"(g0), "+v"(g1), "+v"(g2), "+v"(g3), "+v"(g4), "+v"(g5),  \
                 "+v"(g6), "+v"(g7), "+v"(g8), "+v"(g9), "+v"(g10),           \
                 "+v"(g11), "+v"(g12), "+v"(g13), "+v"(g14), "+v"(g15));

// FMA consumption of a staged group (same order/values as R8 -> bit-identical).
#define MV4(n, i0, i1, i2, i3)        \
  a0 = fmaf(g##n[0], w_##i0, a0);     \
  a1 = fmaf(g##n[1], w_##i1, a1);     \
  a2 = fmaf(g##n[2], w_##i2, a2);     \
  a3 = fmaf(g##n[3], w_##i3, a3);

// In-loop weight pin (R8 had this; removing it in R10 dropped VGPR 72->52 and
// regressed 395->463 µs — the allocator re-shrinks without per-iteration
// liveness pressure).
#define PIN_ALL_W                                                              \
  asm volatile(""                                                              \
               : "+v"(w_0), "+v"(w_1), "+v"(w_2), "+v"(w_3), "+v"(w_4),       \
                 "+v"(w_5), "+v"(w_6), "+v"(w_7), "+v"(w_8), "+v"(w_9),       \
                 "+v"(w_10), "+v"(w_11), "+v"(w_12), "+v"(w_13), "+v"(w_14),  \
                 "+v"(w_15), "+v"(w_16), "+v"(w_17), "+v"(w_18), "+v"(w_19),  \
                 "+v"(w_20), "+v"(w_21), "+v"(w_22), "+v"(w_23), "+v"(w_24),  \
                 "+v"(w_25), "+v"(w_26), "+v"(w_27), "+v"(w_28), "+v"(w_29),  \
                 "+v"(w_30), "+v"(w_31), "+v"(w_32), "+v"(w_33), "+v"(w_34),  \
                 "+v"(w_35), "+v"(w_36), "+v"(w_37), "+v"(w_38), "+v"(w_39),  \
                 "+v"(w_40), "+v"(w_41), "+v"(w_42), "+v"(w_43), "+v"(w_44),  \
                 "+v"(w_45), "+v"(w_46), "+v"(w_47), "+v"(w_48), "+v"(w_49),  \
                 "+v"(w_50), "+v"(w_51), "+v"(w_52), "+v"(w_53), "+v"(w_54),  \
                 "+v"(w_55), "+v"(w_56), "+v"(w_57), "+v"(w_58), "+v"(w_59),  \
                 "+v"(w_60), "+v"(w_61), "+v"(w_62), "+v"(w_63), "+v"(win0),  \
                 "+v"(win1), "+v"(bcj), "+v"(dwout));

// One wave per sample, 1024 blocks = 1 wave/SIMD on all 1024 SIMDs (R7: with
// exactly B=1024 waves, concentrating waves trades SIMD count 1:1 — net loss).
__global__ __launch_bounds__(64, 1) void rnn2d_kernel(
    const int* __restrict__ x, const float* __restrict__ Win,
    const float* __restrict__ Wc, const float* __restrict__ bc,
    const float* __restrict__ Wout, const float* __restrict__ bout,
    float* __restrict__ out) {
  const int lane = threadIdx.x;
  const int b = blockIdx.x;
  __shared__ float vrow[LL * HH];  // vertical carry [column][hidden]
  __shared__ float hvbuf[2 * HH];  // double-buffered hv (step parity)

  DECL_W(0)  DECL_W(1)  DECL_W(2)  DECL_W(3)  DECL_W(4)  DECL_W(5)  DECL_W(6)  DECL_W(7)
  DECL_W(8)  DECL_W(9)  DECL_W(10) DECL_W(11) DECL_W(12) DECL_W(13) DECL_W(14) DECL_W(15)
  DECL_W(16) DECL_W(17) DECL_W(18) DECL_W(19) DECL_W(20) DECL_W(21) DECL_W(22) DECL_W(23)
  DECL_W(24) DECL_W(25) DECL_W(26) DECL_W(27) DECL_W(28) DECL_W(29) DECL_W(30) DECL_W(31)
  DECL_W(32) DECL_W(33) DECL_W(34) DECL_W(35) DECL_W(36) DECL_W(37) DECL_W(38) DECL_W(39)
  DECL_W(40) DECL_W(41) DECL_W(42) DECL_W(43) DECL_W(44) DECL_W(45) DECL_W(46) DECL_W(47)
  DECL_W(48) DECL_W(49) DECL_W(50) DECL_W(51) DECL_W(52) DECL_W(53) DECL_W(54) DECL_W(55)
  DECL_W(56) DECL_W(57) DECL_W(58) DECL_W(59) DECL_W(60) DECL_W(61) DECL_W(62) DECL_W(63)

  float win0 = Win[lane];
  float win1 = Win[HH + lane];
  float bcj = bc[lane];
  float dwout = Wout[lane * 2 + 1] - Wout[lane * 2 + 0];
  const float dbout = bout[1] - bout[0];

  // Row 0 sees zero vertical hidden carry; step-0 hv is also zero.
#pragma unroll
  for (int c0 = 0; c0 < LL; ++c0) vrow[c0 * HH + lane] = 0.f;
  hvbuf[lane] = 0.f;  // buffer 0 holds hv for the very first step

  const int* xb = x + b * (LL * LL);
  unsigned prevmask = 0u;                // previous row's spins (bit c = spin at col c)
  int spv = (lane < LL) ? xb[lane] : 0;  // prefetched row-0 spins
  float total_vec = 0.f;                 // per-lane partial of sum(logp)
  float dzbuf = 0.f;                     // lane k holds step-k signed logit gap

#pragma unroll 1
  for (int r = 0; r < LL; ++r) {
    const unsigned curmask =
        (unsigned)(__ballot(lane < LL && spv) & 0xffffffffull);
    if (r < LL - 1) spv = (lane < LL) ? xb[(r + 1) * LL + lane] : 0;

    const int odd = r & 1;
    const int d = odd ? -1 : 1;       // boustrophedon direction
    int c = odd ? (LL - 1) : 0;       // spatial column of scan step 0

#pragma unroll 2
    for (int k = 0; k < LL; ++k) {
      PIN_ALL_W

      // Wave-uniform broadcast source for this step's hv (parity buffer).
      const f32x4* hv4 = (const f32x4*)(hvbuf + ((k & 1) ? HH : 0));

      // Prefetch next step's vertical carry (lane-strided, conflict-free;
      // that column is not yet overwritten this row).
      const int cn = (c + d) & (LL - 1);
      const float vjn = vrow[cn * HH + lane];

      // Stage ALL 16 broadcast reads, then pin -> reads pipeline at LDS
      // throughput instead of serializing on consumption.
      LOADG(0)  LOADG(1)  LOADG(2)  LOADG(3)  LOADG(4)  LOADG(5)  LOADG(6)  LOADG(7)
      LOADG(8)  LOADG(9)  LOADG(10) LOADG(11) LOADG(12) LOADG(13) LOADG(14) LOADG(15)
      PIN_ALL_G

      // newH[j] = sum_i hv[i]*Wc[i][j]: 64 FMAs, 4 independent chains.
      float a0 = 0.f, a1 = 0.f, a2 = 0.f, a3 = 0.f;
      MV4(0, 0, 1, 2, 3)      MV4(1, 4, 5, 6, 7)      MV4(2, 8, 9, 10, 11)
      MV4(3, 12, 13, 14, 15)  MV4(4, 16, 17, 18, 19)  MV4(5, 20, 21, 22, 23)
      MV4(6, 24, 25, 26, 27)  MV4(7, 28, 29, 30, 31)  MV4(8, 32, 33, 34, 35)
      MV4(9, 36, 37, 38, 39)  MV4(10, 40, 41, 42, 43) MV4(11, 44, 45, 46, 47)
      MV4(12, 48, 49, 50, 51) MV4(13, 52, 53, 54, 55) MV4(14, 56, 57, 58, 59)
      MV4(15, 60, 61, 62, 63)

      // newR @ Win: one-hot selects (spins are wave-uniform bits of the masks).
      float winc = 0.f;
      if (k > 0) {
        const unsigned sh = (curmask >> ((c - d) & 31)) & 1u;
        winc += sh ? win1 : win0;
      }
      if (r > 0) {
        const unsigned sv = (prevmask >> c) & 1u;
        winc += sv ? win1 : win0;
      }

      const float pre = ((a0 + a1) + (a2 + a3)) + bcj + winc;
      const float hnew = pre > 0.f ? pre : (__expf(pre) - 1.f);  // elu

      vrow[c * HH + lane] = hnew;  // vertical carry for next row

      // Store next step's hv IMMEDIATELY (hides the LDS write->read round trip
      // behind the logp tail below). At k==31 the next step is the next row's
      // step 0: re-enters this same column with zero horizontal carry.
      const float hvn = hnew + ((k < LL - 1) ? vjn : 0.f);
      hvbuf[((k & 1) ? 0 : HH) + lane] = hvn;

      // Deferred logp: stash signed logit gap t_k in lane k; softplus once/row.
      const float dzv = wave_sum64(hnew * dwout) + dbout;  // z1 - z0, uniform
      const unsigned spin = (curmask >> c) & 1u;
      const float tv = __builtin_bit_cast(
          float, __builtin_bit_cast(unsigned, dzv) ^ (spin << 31));
      dzbuf = (lane == k) ? tv : dzbuf;

      c = cn;
    }
    prevmask = curmask;

    // Row epilogue: softplus for all 32 steps at once (lanes 0..31 hold t_k).
    const float tt = dzbuf;
    float lpv = -(fmaxf(tt, 0.f) + __logf(1.f + __expf(-fabsf(tt))));
    lpv = (lpv == lpv) ? lpv : -35.0f;  // nan_to_num(nan=-35)
    total_vec += (lane < LL) ? lpv : 0.f;
  }

  const float grand = wave_sum64(total_vec);
  if (lane == 0) out[b] = 0.5f * grand;  // LOGP_FACTOR * sum
}

extern "C" void kernel_launch(void* const* d_in, const int* in_sizes, int n_in,
                              void* d_out, int out_size, void* d_ws, size_t ws_size,
                              hipStream_t stream) {
  const int* x = (const int*)d_in[0];
  const float* Win = (const float*)d_in[1];
  const float* Wc = (const float*)d_in[2];
  const float* bc = (const float*)d_in[3];
  const float* Wout = (const float*)d_in[4];
  const float* bout = (const float*)d_in[5];
  float* out = (float*)d_out;
  rnn2d_kernel<<<dim3(out_size), dim3(64), 0, stream>>>(x, Win, Wc, bc, Wout, bout, out);
}